// Round 14
// baseline (224.077 us; speedup 1.0000x reference)
//
#include <hip/hip_runtime.h>
#include <stdint.h>

// LateralInhibition: out = inputs * ((inputs @ w1 + b) > 0), w1 = w with zero diag.
// v14 = v13 (PASSED 203.6us; li_mfma 130us) with the A-lo plane DROPPED and the
//       direct-store epilogue restored.
//  - numerics: a ~ ah only (f16 rel err 2^-11); W keeps hi+lo. err = sum a_lo*w:
//    Bernstein (cap 3.6e-5/term, sigma 6.4e-5) -> P(|err|>1e-3) ~ 3e-14/elem,
//    ~5e-7 expected unflagged escapes in 16.7M. |inh|<=1e-3 still flagged and
//    exactly recomputed in-kernel (v4's k-ascending fmaf chain, bit-identical).
//    [Dropping BOTH lo planes rejected: ~2 expected escapes.]
//  - structure wins: LDS 68->50 KB/block -> 3 blocks/CU (12 waves, was 8);
//    MFMA count -33% (2/frag: ah*bh + ah*bl); ACONV VALU -60%; A ds_writes
//    halved; cbuf epilogue round-trip deleted (v13's +23us regression), direct
//    float-store epilogue + LDS flag list + inline fix kept.
// Numerics otherwise v11..v13-proven: A*2^12 (in-kernel cvt), W*2^13 (prep,
// tiled+swizzled), single acc at 2^25, /2^25 exact epilogue.
// Structure: 128x128 tile, 4 waves 2x2, B via global_load_lds from pre-tiled
// ws (1KB contiguous per DMA), A reg-staged+converted in-kernel, 2-buffer
// __syncthreads schedule, XCD-chunked swizzle.

#define NUMD 512
#define EPS 1e-3f
#define FLCAP 512u                   // per-block fix-list capacity (mean ~29)
#define SA 4096.0f                   // 2^12
#define SW 8192.0f                   // 2^13
#define INV_S (1.0f / 33554432.0f)   // 2^-25
#define TILE_F16 4096                // 128*32 f16 per tile
#define SLAB_F16 (16 * TILE_F16)     // 16 k-tiles per slab

typedef _Float16 f16;
typedef _Float16 f16x8 __attribute__((ext_vector_type(8)));
typedef float    f32x4 __attribute__((ext_vector_type(4)));

#define GLOAD_LDS16(g, l)                                                      \
  __builtin_amdgcn_global_load_lds(                                            \
      (const __attribute__((address_space(1))) void*)(g),                      \
      (__attribute__((address_space(3))) void*)(l), 16, 0, 0)

// -------- pre-pass (W only): transpose + diag-zero + scaled f16 split, tiled --------
// Tiled layout: plane[slab][kt][row][chunk p][8], p = c ^ ((row>>1)&3).
__global__ __launch_bounds__(256) void prep(
    const float* __restrict__ W, float* __restrict__ Wt,
    f16* __restrict__ WtH, f16* __restrict__ WtL)
{
    const int n = blockIdx.x;
    const int slab = n >> 7, rn = n & 127;
    const int srow = (rn >> 1) & 3;
    for (int k = threadIdx.x; k < NUMD; k += 256) {
        float v = W[(size_t)k * NUMD + n];
        if (k == n) v = 0.0f;
        Wt[(size_t)n * NUMD + k] = v;          // unscaled fp32 for inline fix
        const float vs = v * SW;
        f16 h  = (f16)vs;
        f16 lo = (f16)(vs - (float)h);         // unscaled residual
        const int kt = k >> 5, kk = k & 31, c = kk >> 3, e = kk & 7;
        const int p = c ^ srow;
        const size_t off = (size_t)slab * SLAB_F16 + (size_t)kt * TILE_F16
                         + rn * 32 + p * 8 + e;
        WtH[off] = h; WtL[off] = lo;
    }
}

// ---------------- main GEMM (A-hi only, fused cvt + inline fixup) ----------------
__global__ __launch_bounds__(256) void li_mfma(
    const float* __restrict__ A,    // [M,512] fp32
    const f16* __restrict__ WtH, const f16* __restrict__ WtL, // tiled
    const float* __restrict__ Wt,   // [n][k] fp32 diag-zeroed (inline fix)
    const float* __restrict__ bias,
    float* __restrict__ out,
    int M, int cpx)
{
    // [2 bufs][3 planes: AH BH BL][128 rows][32 k] f16 = 48 KiB -> 3 blocks/CU
    __shared__ __align__(16) f16 lds[2][3][128][32];
    __shared__ unsigned flist[FLCAP];
    __shared__ unsigned lcnt;

    const int tid = threadIdx.x;
    const int l   = tid & 63;
    const int wv  = tid >> 6;     // wave 0..3
    const int wr  = wv >> 1;      // wave row 0..1
    const int wc  = wv & 1;       // wave col 0..1
    const int lG  = l >> 4;       // k-chunk group 0..3
    const int lM  = l & 15;       // frag row/col

    int w = blockIdx.x;
    if (cpx) { const int xcd = w & 7, c = w >> 3; w = xcd * cpx + c; }
    const int m0  = (w >> 2) * 128;
    const int n0b = (w & 3) * 128;

    // ---- B DMA source (tiled planes, contiguous 1KB per instruction)
    const size_t bOff = ((size_t)(n0b >> 7) * SLAB_F16) * 2 + wv * 2048 + l * 16;
    const char* pBH = (const char*)WtH;
    const char* pBL = (const char*)WtL;

#define STAGE_B(nb, ktb) do {                                                  \
    GLOAD_LDS16(pBH + bOff + (ktb),        &lds[nb][1][wv * 32][0]);           \
    GLOAD_LDS16(pBH + bOff + (ktb) + 1024, &lds[nb][1][wv * 32 + 16][0]);      \
    GLOAD_LDS16(pBL + bOff + (ktb),        &lds[nb][2][wv * 32][0]);           \
    GLOAD_LDS16(pBL + bOff + (ktb) + 1024, &lds[nb][2][wv * 32 + 16][0]);      \
  } while (0)

    // ---- A staging (reg path): tasks {tid, tid+256}; row=i>>2, chunk c=i&3.
    const int r0 = tid >> 2, ca = tid & 3;
    const int r1 = r0 + 64;
    const float* aBase0 = A + (size_t)(m0 + r0) * NUMD + ca * 8;
    const float* aBase1 = A + (size_t)(m0 + r1) * NUMD + ca * 8;
    const int wo0 = r0 * 64 + ((ca ^ ((r0 >> 1) & 3)) << 4);
    const int wo1 = r1 * 64 + ((ca ^ ((r1 >> 1) & 3)) << 4);

    float4 av00, av01, av10, av11;

#define ALOAD(kt) do {                                                         \
    const float* s0 = aBase0 + (size_t)(kt) * 32;                              \
    const float* s1 = aBase1 + (size_t)(kt) * 32;                              \
    av00 = *(const float4*)s0; av01 = *(const float4*)(s0 + 4);                \
    av10 = *(const float4*)s1; av11 = *(const float4*)(s1 + 4);                \
  } while (0)

#define ACONV(nb) do {                                                         \
    const float a0[8] = {av00.x, av00.y, av00.z, av00.w,                       \
                         av01.x, av01.y, av01.z, av01.w};                      \
    const float a1[8] = {av10.x, av10.y, av10.z, av10.w,                       \
                         av11.x, av11.y, av11.z, av11.w};                      \
    f16x8 h0, h1;                                                              \
    _Pragma("unroll")                                                          \
    for (int e = 0; e < 8; ++e) {                                              \
        h0[e] = (f16)(a0[e] * SA);                                             \
        h1[e] = (f16)(a1[e] * SA);                                             \
    }                                                                          \
    *(f16x8*)((char*)&lds[nb][0][0][0] + wo0) = h0;                            \
    *(f16x8*)((char*)&lds[nb][0][0][0] + wo1) = h1;                            \
  } while (0)

    int aRd[4], bRd[4];
#pragma unroll
    for (int f = 0; f < 4; ++f) {
        const int mr = wr * 64 + f * 16 + lM;
        aRd[f] = mr * 64 + ((lG ^ ((mr >> 1) & 3)) << 4);
        const int nr = wc * 64 + f * 16 + lM;
        bRd[f] = nr * 64 + ((lG ^ ((nr >> 1) & 3)) << 4);
    }

    f32x4 acc[4][4];
#pragma unroll
    for (int i = 0; i < 4; ++i)
#pragma unroll
        for (int j = 0; j < 4; ++j) acc[i][j] = f32x4{0.f, 0.f, 0.f, 0.f};

    // prologue: tile 0
    ALOAD(0);
    STAGE_B(0, 0);
    ACONV(0);

    const int NT = NUMD / 32;   // 16
    for (int kt = 0; kt < NT; ++kt) {
        const int cur = kt & 1;
        __syncthreads();        // publishes tile kt (DMA vmcnt + ds_writes + barrier)

        if (kt + 1 < NT) {
            STAGE_B(cur ^ 1, (size_t)(kt + 1) * 8192);
            ALOAD(kt + 1);
        }

        const char* PAH = (const char*)&lds[cur][0][0][0];
        const char* PBH = (const char*)&lds[cur][1][0][0];
        const char* PBL = (const char*)&lds[cur][2][0][0];

        f16x8 bh[4], bl[4];
#pragma unroll
        for (int fj = 0; fj < 4; ++fj) {
            bh[fj] = *(const f16x8*)(PBH + bRd[fj]);
            bl[fj] = *(const f16x8*)(PBL + bRd[fj]);
        }
        __builtin_amdgcn_s_setprio(1);
#pragma unroll
        for (int fi = 0; fi < 4; ++fi) {
            const f16x8 ah = *(const f16x8*)(PAH + aRd[fi]);
#pragma unroll
            for (int fj = 0; fj < 4; ++fj) {
                acc[fi][fj] = __builtin_amdgcn_mfma_f32_16x16x32_f16(ah, bh[fj], acc[fi][fj], 0, 0, 0);
                acc[fi][fj] = __builtin_amdgcn_mfma_f32_16x16x32_f16(ah, bl[fj], acc[fi][fj], 0, 0, 0);
            }
        }
        __builtin_amdgcn_s_setprio(0);

        if (kt + 1 < NT) ACONV(cur ^ 1);
    }

    // ================= epilogue (direct stores, v12-style) =================
    __syncthreads();
    if (tid == 0) lcnt = 0;
    __syncthreads();

    // C/D layout col=lane&15, row=(lane>>4)*4+reg (m89-verified)
#pragma unroll
    for (int fj = 0; fj < 4; ++fj) {
        const int n = n0b + wc * 64 + fj * 16 + lM;
        const float bvj = bias[n];
#pragma unroll
        for (int fi = 0; fi < 4; ++fi) {
            const int mb = m0 + wr * 64 + fi * 16 + lG * 4;
#pragma unroll
            for (int r = 0; r < 4; ++r) {
                const size_t idx = (size_t)(mb + r) * NUMD + n;
                const float inh = acc[fi][fj][r] * INV_S + bvj;
                const float x = A[idx];
                out[idx] = (inh > 0.0f) ? x : 0.0f;
                if (__builtin_fabsf(inh) <= EPS) {
                    unsigned p = atomicAdd(&lcnt, 1u);   // LDS atomic
                    if (p < FLCAP) flist[p] = (unsigned)idx;
                }
            }
        }
    }

    // inline fix: exact fp32 recompute, BIT-IDENTICAL op order to the proven
    // v4 path (k-ascending fmaf chain). __syncthreads drains the bulk stores
    // (vmcnt 0) before the fix overwrites the same addresses.
    __syncthreads();
    unsigned nf = lcnt; if (nf > FLCAP) nf = FLCAP;
    for (unsigned e = tid; e < nf; e += 256) {
        const unsigned code = flist[e];
        const int n = (int)(code & 511);
        const float* ar  = A  + (size_t)(code >> 9) * NUMD;
        const float* wr_ = Wt + (size_t)n * NUMD;
        float s = 0.0f;
#pragma unroll 8
        for (int k = 0; k < NUMD; ++k)
            s = fmaf(ar[k], wr_[k], s);        // strict k-ascending chain
        const float inh = s + bias[n];
        out[code] = (inh > 0.0f) ? A[code] : 0.0f;
    }
#undef STAGE_B
#undef ALOAD
#undef ACONV
}

// ---------------- fallback: v4 exact fp32 path (proven 205us) ----------------
#define BM 128
#define BN 256
#define BK 16
#define TM 8
#define TN 16
#define NTF (NUMD / BK)

__global__ __launch_bounds__(256) void zero_diag_kernel(
    const float* __restrict__ W, float* __restrict__ Wz)
{
    const int f = (int)(blockIdx.x * blockDim.x + threadIdx.x) * 4;
    const int row = f >> 9, col0 = f & 511;
    float4 v = *(const float4*)(W + f);
    if (row == col0 + 0) v.x = 0.0f;
    if (row == col0 + 1) v.y = 0.0f;
    if (row == col0 + 2) v.z = 0.0f;
    if (row == col0 + 3) v.w = 0.0f;
    *(float4*)(Wz + f) = v;
}

template<bool ZDIAG>
__global__ __launch_bounds__(256, 1) void li_gemm_fp32(
    const float* __restrict__ A, const float* __restrict__ Wm,
    const float* __restrict__ bias, float* __restrict__ out, int M)
{
    __shared__ __align__(16) float As[2][BM][BK];
    __shared__ __align__(16) float Bs[2][BK][BN];
    const int tid = threadIdx.x, lane = tid & 63, wv = tid >> 6;
    const int tc = tid & 15, tr = tid >> 4;
    const int m0 = blockIdx.x * BM, n0 = blockIdx.y * BN;
    const int am0 = wv * 32 + (lane >> 2), am1 = am0 + 16;
    const int q0 = ((lane & 3) ^ ((am0 >> 3) & 3)) << 2;
    const int q1 = ((lane & 3) ^ ((am1 >> 3) & 3)) << 2;
    const float* aSrc0 = A + (size_t)(m0 + am0) * NUMD + q0;
    const float* aSrc1 = A + (size_t)(m0 + am1) * NUMD + q1;
    const float* wSrc = Wm + (size_t)(wv * 4) * NUMD + n0 + lane * 4;
    float acc[TM][TN];
#pragma unroll
    for (int i = 0; i < TM; ++i)
#pragma unroll
        for (int j = 0; j < TN; ++j) acc[i][j] = 0.0f;
    GLOAD_LDS16(aSrc0, &As[0][wv * 32][0]);
    GLOAD_LDS16(aSrc1, &As[0][wv * 32 + 16][0]);
#pragma unroll
    for (int r = 0; r < 4; ++r)
        GLOAD_LDS16(wSrc + (size_t)r * NUMD, &Bs[0][wv * 4 + r][0]);
    aSrc0 += BK; aSrc1 += BK; wSrc += (size_t)BK * NUMD;
    for (int kt = 0; kt < NTF; ++kt) {
        const int cur = kt & 1;
        __syncthreads();
        if (kt + 1 < NTF) {
            const int nb = cur ^ 1;
            GLOAD_LDS16(aSrc0, &As[nb][wv * 32][0]);
            GLOAD_LDS16(aSrc1, &As[nb][wv * 32 + 16][0]);
#pragma unroll
            for (int r = 0; r < 4; ++r)
                GLOAD_LDS16(wSrc + (size_t)r * NUMD, &Bs[nb][wv * 4 + r][0]);
            aSrc0 += BK; aSrc1 += BK; wSrc += (size_t)BK * NUMD;
        }
        if (ZDIAG) {
            const int kk = kt * BK;
            if (tid < BK) {
                const int col = kk + tid - n0;
                if (col >= 0 && col < BN) Bs[cur][tid][col] = 0.0f;
            }
            __syncthreads();
        }
#pragma unroll
        for (int g = 0; g < 4; ++g) {
            float4 af[TM];
#pragma unroll
            for (int i = 0; i < TM; ++i) {
                const int m = tr * TM + i;
                af[i] = *(const float4*)&As[cur][m][(g ^ ((m >> 3) & 3)) << 2];
            }
#pragma unroll
            for (int dk = 0; dk < 4; ++dk) {
                float b[TN];
#pragma unroll
                for (int c = 0; c < 4; ++c) {
                    float4 b4 = *(const float4*)&Bs[cur][g * 4 + dk][tc * 4 + 64 * c];
                    b[4*c+0] = b4.x; b[4*c+1] = b4.y; b[4*c+2] = b4.z; b[4*c+3] = b4.w;
                }
#pragma unroll
                for (int i = 0; i < TM; ++i) {
                    const float a = ((const float*)&af[i])[dk];
#pragma unroll
                    for (int j = 0; j < TN; ++j) acc[i][j] = fmaf(a, b[j], acc[i][j]);
                }
            }
        }
    }
    float bv[TN];
#pragma unroll
    for (int c = 0; c < 4; ++c) {
        float4 b4 = *(const float4*)(bias + n0 + tc * 4 + 64 * c);
        bv[4*c+0] = b4.x; bv[4*c+1] = b4.y; bv[4*c+2] = b4.z; bv[4*c+3] = b4.w;
    }
#pragma unroll
    for (int i = 0; i < TM; ++i) {
        const int gm = m0 + tr * TM + i;
        const float* inrow = A + (size_t)gm * NUMD + n0 + tc * 4;
        float* orow = out + (size_t)gm * NUMD + n0 + tc * 4;
#pragma unroll
        for (int c = 0; c < 4; ++c) {
            float4 x = *(const float4*)(inrow + 64 * c);
            float4 o;
            o.x = (acc[i][4*c+0] + bv[4*c+0] > 0.0f) ? x.x : 0.0f;
            o.y = (acc[i][4*c+1] + bv[4*c+1] > 0.0f) ? x.y : 0.0f;
            o.z = (acc[i][4*c+2] + bv[4*c+2] > 0.0f) ? x.z : 0.0f;
            o.w = (acc[i][4*c+3] + bv[4*c+3] > 0.0f) ? x.w : 0.0f;
            *(float4*)(orow + 64 * c) = o;
        }
    }
}

extern "C" void kernel_launch(void* const* d_in, const int* in_sizes, int n_in,
                              void* d_out, int out_size, void* d_ws, size_t ws_size,
                              hipStream_t stream) {
    const float* A    = (const float*)d_in[0];
    const float* W    = (const float*)d_in[1];
    const float* bias = (const float*)d_in[2];
    float* out        = (float*)d_out;
    const int M = in_sizes[0] / NUMD;           // 32768

    const size_t need = (2u << 20) + 4096;

    if (ws_size >= need) {
        char* wsb = (char*)d_ws;
        float* Wt  = (float*)wsb;                              // 1 MiB
        f16*   WtH = (f16*)(wsb + (1u << 20));                 // 512 KiB tiled
        f16*   WtL = (f16*)(wsb + (1u << 20) + (512u << 10));  // 512 KiB tiled

        prep<<<dim3(NUMD), 256, 0, stream>>>(W, Wt, WtH, WtL);
        const int nwg = (M / 128) * (NUMD / 128);
        const int cpx = (nwg % 8 == 0) ? (nwg / 8) : 0;
        li_mfma<<<dim3(nwg), 256, 0, stream>>>(A, WtH, WtL, Wt, bias, out,
                                               M, cpx);
    } else {
        dim3 grid(M / BM, NUMD / BN);
        const size_t wbytes = (size_t)NUMD * NUMD * sizeof(float);
        if (ws_size >= wbytes) {
            float* Wz = (float*)d_ws;
            zero_diag_kernel<<<dim3(NUMD * NUMD / (4 * 256)), 256, 0, stream>>>(W, Wz);
            li_gemm_fp32<false><<<grid, 256, 0, stream>>>(A, Wz, bias, out, M);
        } else {
            li_gemm_fp32<true><<<grid, 256, 0, stream>>>(A, W, bias, out, M);
        }
    }
}